// Round 10
// baseline (235.722 us; speedup 1.0000x reference)
//
#include <hip/hip_runtime.h>

namespace {

constexpr int B_  = 2;
constexpr int N_  = 512;
constexpr int IN_ = 512;
constexpr int M_  = 300;   // MEM
constexpr int H_  = 64;    // HID
constexpr float SLOPE_ = 0.01f;

// ---- workspace layout (float offsets). No memsets, no atomics: every buffer
// is fully written by plain stores before it is read. ----
constexpr long OFF_W0AI = 0;                          // 512 x 64
constexpr long OFF_W0AJ = OFF_W0AI + 512L * 64;
constexpr long OFF_W1AI = OFF_W0AJ + 512L * 64;       // 300 x 64
constexpr long OFF_W1AJ = OFF_W1AI + 300L * 64;
constexpr long OFF_BSI0 = OFF_W1AJ + 300L * 64;       // 4 x 64 bias combos
constexpr long OFF_BSJ0 = OFF_BSI0 + 64;
constexpr long OFF_BSI1 = OFF_BSJ0 + 64;
constexpr long OFF_BSJ1 = OFF_BSI1 + 64;
constexpr long OFF_H0   = OFF_BSJ1 + 64;              // 1024 x 300
constexpr long OFF_SI0  = OFF_H0   + 1024L * 300;     // 1024 x 64
constexpr long OFF_SJ0  = OFF_SI0  + 1024L * 64;
constexpr long OFF_F1   = OFF_SJ0  + 1024L * 64;      // 1024 x 300
constexpr long OFF_H1   = OFF_F1   + 1024L * 300;
constexpr long OFF_SI1  = OFF_H1   + 1024L * 300;
constexpr long OFF_SJ1  = OFF_SI1  + 1024L * 64;
constexpr long OFF_ZP0  = OFF_SJ1  + 1024L * 64;      // 2 x 256 partial sums
constexpr long OFF_ZP1  = OFF_ZP0  + 512;
constexpr long OFF_P0   = OFF_ZP1  + 512;             // 2 x 512 x 512
constexpr long OFF_P1   = OFF_P0   + 2L * 512 * 512;  // total ~9.4 MB

// ---------------------------------------------------------------------------
// Multi-job fp32 GEMM: blockIdx.x -> (job, tile) via prefix offsets.
// Tile 32x64, 128 threads (2 waves), 4x4 micro-tile, TK=32, register prefetch.
//   2 B LDS / FMA (4x4) AND R6's block counts (224 for the wide dispatches,
//   ~1 block/CU) — fixes R8 (fat tile, half the CUs) and R7 (1 wave, no
//   latency hiding). Per-wave k-step: 2 ds_read_b128 + 16 v_fma.
//   C = (Zp ? 1/sum(Zp[0..255]) : 1) * A@W + bias
// Bank layout: A staged transposed, stride 36, k-split (sk, sk+16) => 2-way
// max (free). Compute reads: As/Ws broadcast-aligned b128.
// All tails guarded (zero-fill LDS, row clamp for R=1 jobs, predicated store).
// ---------------------------------------------------------------------------
struct Jobs {
    const float* A[8]; const float* W[8]; const float* bias[8]; const float* Zp[8];
    float* C[8];
    int K[8]; int lda[8]; int Cc[8]; int R[8];
    int off[8]; int njobs;
};

__global__ __launch_bounds__(128)
void gemm_multi(Jobs jb)
{
    __shared__ __align__(16) float As[32][36];  // [k][m]
    __shared__ __align__(16) float Ws[32][64];  // [k][n]

    const int bid = blockIdx.x;
    int j = jb.njobs - 1;
    while (j > 0 && bid < jb.off[j]) --j;
    const int local = bid - jb.off[j];

    const float* __restrict__ A = jb.A[j];
    const float* __restrict__ W = jb.W[j];
    const float* bias = jb.bias[j];
    const float* Zp   = jb.Zp[j];
    float* __restrict__ C = jb.C[j];
    const int K = jb.K[j], lda = jb.lda[j], Cc = jb.Cc[j], R = jb.R[j];

    const int tx   = (Cc + 63) >> 6;
    const int row0 = (local / tx) * 32;
    const int col0 = (local % tx) * 64;

    const int t    = threadIdx.x;
    const int sr   = t >> 2;              // A row 0..31
    const int sk   = (t & 3) * 4;         // A k-offsets sk and sk+16
    const int arow = min(row0 + sr, R - 1);
    const int wk   = t >> 4;              // W k-rows wk+8s, s=0..3
    const int wc   = (t & 15) * 4;
    const int tm0  = (t >> 4) * 4;        // 0..28
    const int tn0  = (t & 15) * 4;        // 0..60

    auto loadA4 = [&](int k) -> float4 {  // A[arow][k..k+3], guarded
        if (k + 3 < K) return *(const float4*)(A + (long)arow * lda + k);
        float tv[4];
        #pragma unroll
        for (int v = 0; v < 4; ++v)
            tv[v] = (k + v < K) ? A[(long)arow * lda + k + v] : 0.0f;
        return make_float4(tv[0], tv[1], tv[2], tv[3]);
    };
    auto loadW4 = [&](int gk) -> float4 { // W[gk][col0+wc..+3], guarded
        const int c = col0 + wc;
        if (gk < K && c + 3 < Cc) return *(const float4*)(W + (long)gk * Cc + c);
        float tv[4];
        #pragma unroll
        for (int v = 0; v < 4; ++v)
            tv[v] = (gk < K && c + v < Cc) ? W[(long)gk * Cc + c + v] : 0.0f;
        return make_float4(tv[0], tv[1], tv[2], tv[3]);
    };

    float acc[4][4] = {};
    float4 a0v = loadA4(sk), a1v = loadA4(16 + sk);
    float4 w0v = loadW4(wk), w1v = loadW4(wk + 8),
           w2v = loadW4(wk + 16), w3v = loadW4(wk + 24);

    for (int k0 = 0; k0 < K; k0 += 32) {
        As[sk + 0][sr] = a0v.x;           // transposed; 2-way banks (free)
        As[sk + 1][sr] = a0v.y;
        As[sk + 2][sr] = a0v.z;
        As[sk + 3][sr] = a0v.w;
        As[16 + sk + 0][sr] = a1v.x;
        As[16 + sk + 1][sr] = a1v.y;
        As[16 + sk + 2][sr] = a1v.z;
        As[16 + sk + 3][sr] = a1v.w;
        *(float4*)&Ws[wk][wc]      = w0v;
        *(float4*)&Ws[wk +  8][wc] = w1v;
        *(float4*)&Ws[wk + 16][wc] = w2v;
        *(float4*)&Ws[wk + 24][wc] = w3v;
        __syncthreads();

        if (k0 + 32 < K) {                // prefetch next slab behind compute
            a0v = loadA4(k0 + 32 + sk);
            a1v = loadA4(k0 + 48 + sk);
            w0v = loadW4(k0 + 32 + wk);
            w1v = loadW4(k0 + 40 + wk);
            w2v = loadW4(k0 + 48 + wk);
            w3v = loadW4(k0 + 56 + wk);
        }

        #pragma unroll
        for (int k = 0; k < 32; ++k) {
            const float4 a4 = *(const float4*)&As[k][tm0];
            const float4 w4 = *(const float4*)&Ws[k][tn0];
            const float aa[4] = {a4.x, a4.y, a4.z, a4.w};
            const float ww[4] = {w4.x, w4.y, w4.z, w4.w};
            #pragma unroll
            for (int i = 0; i < 4; ++i)
                #pragma unroll
                for (int jj = 0; jj < 4; ++jj)
                    acc[i][jj] = fmaf(aa[i], ww[jj], acc[i][jj]);
        }
        __syncthreads();
    }

    float scale = 1.0f;
    if (Zp != nullptr) {                  // softmax denom from tile partials
        const float4* z4 = (const float4*)Zp;
        float4 s = make_float4(0.f, 0.f, 0.f, 0.f);
        #pragma unroll 8
        for (int u = 0; u < 64; ++u) {
            const float4 v = z4[u];
            s.x += v.x; s.y += v.y; s.z += v.z; s.w += v.w;
        }
        scale = 1.0f / ((s.x + s.y) + (s.z + s.w));
    }
    const int cbase = col0 + tn0;
    float bv[4] = {0.f, 0.f, 0.f, 0.f};
    if (bias != nullptr) {
        #pragma unroll
        for (int u = 0; u < 4; ++u)
            if (cbase + u < Cc) bv[u] = bias[cbase + u];
    }
    #pragma unroll
    for (int i = 0; i < 4; ++i) {
        const int r = row0 + tm0 + i;
        if (r < R) {
            if (cbase + 3 < Cc) {
                float4 o;
                o.x = fmaf(acc[i][0], scale, bv[0]);
                o.y = fmaf(acc[i][1], scale, bv[1]);
                o.z = fmaf(acc[i][2], scale, bv[2]);
                o.w = fmaf(acc[i][3], scale, bv[3]);
                *(float4*)(C + (long)r * Cc + cbase) = o;
            } else {
                #pragma unroll
                for (int u = 0; u < 4; ++u)
                    if (cbase + u < Cc)
                        C[(long)r * Cc + cbase + u] = fmaf(acc[i][u], scale, bv[u]);
            }
        }
    }
}

// ---------------------------------------------------------------------------
// Attention numerator (32i x 32j tile per block):
//   e = leaky_relu( sum_h relu(si[i,h]+sj[j,h]) * a2w[h] + a2b )
//   p = adj * exp(e);  Zpart[b*256+tile] = sum(p)  (plain store — no atomics)
// Max-subtraction skipped: |e| = O(10), fp32 exp exact-safe; softmax is over
// the flat N*N per batch so sum(Zpart) is the exact denominator.
// ---------------------------------------------------------------------------
__global__ __launch_bounds__(256)
void attn_p_kernel(const float* __restrict__ si, const float* __restrict__ sj,
                   const float* __restrict__ adj, const float* __restrict__ a2w,
                   const float* __restrict__ a2b, float* __restrict__ p,
                   float* __restrict__ Zpart)
{
    __shared__ __align__(16) float Si[32][68];
    __shared__ __align__(16) float Sj[32][68];

    const int b  = blockIdx.z;
    const int i0 = blockIdx.y * 32;
    const int j0 = blockIdx.x * 32;
    const int t  = threadIdx.x;

    {   // stage 32x64 tiles of si and sj
        const int r  = t >> 3;
        const int hc = (t & 7) * 8;
        const float* gi = si + ((long)(b * N_ + i0 + r)) * H_ + hc;
        const float* gj = sj + ((long)(b * N_ + j0 + r)) * H_ + hc;
        *(float4*)&Si[r][hc]     = *(const float4*)(gi);
        *(float4*)&Si[r][hc + 4] = *(const float4*)(gi + 4);
        *(float4*)&Sj[r][hc]     = *(const float4*)(gj);
        *(float4*)&Sj[r][hc + 4] = *(const float4*)(gj + 4);
    }
    __syncthreads();

    const int i  = t >> 3;
    const int jl = t & 7;

    float e[4] = {0.f, 0.f, 0.f, 0.f};
    #pragma unroll
    for (int h0 = 0; h0 < H_; h0 += 4) {
        const float4 a4 = *(const float4*)&Si[i][h0];
        const float w0v = a2w[h0 + 0];
        const float w1v = a2w[h0 + 1];
        const float w2v = a2w[h0 + 2];
        const float w3v = a2w[h0 + 3];
        #pragma unroll
        for (int u = 0; u < 4; ++u) {
            const float4 b4 = *(const float4*)&Sj[jl + 8 * u][h0];
            e[u] = fmaf(fmaxf(a4.x + b4.x, 0.f), w0v, e[u]);
            e[u] = fmaf(fmaxf(a4.y + b4.y, 0.f), w1v, e[u]);
            e[u] = fmaf(fmaxf(a4.z + b4.z, 0.f), w2v, e[u]);
            e[u] = fmaf(fmaxf(a4.w + b4.w, 0.f), w3v, e[u]);
        }
    }

    const float a2bv = a2b[0];
    const long rowbase = ((long)(b * N_ + i0 + i)) * N_ + j0 + jl;
    float lsum = 0.f;
    #pragma unroll
    for (int u = 0; u < 4; ++u) {
        float ev = e[u] + a2bv;
        ev = (ev >= 0.f) ? ev : SLOPE_ * ev;
        const float m  = adj[rowbase + 8 * u];
        const float pv = m * __expf(ev);
        p[rowbase + 8 * u] = pv;
        lsum += pv;
    }

    #pragma unroll
    for (int off = 32; off > 0; off >>= 1)
        lsum += __shfl_down(lsum, off, 64);
    __shared__ float red[4];
    if ((t & 63) == 0) red[t >> 6] = lsum;
    __syncthreads();
    if (t == 0)
        Zpart[b * 256 + blockIdx.y * 16 + blockIdx.x] =
            red[0] + red[1] + red[2] + red[3];
}

} // namespace

extern "C" void kernel_launch(void* const* d_in, const int* in_sizes, int n_in,
                              void* d_out, int out_size, void* d_ws, size_t ws_size,
                              hipStream_t stream)
{
    const float* feature = (const float*)d_in[0];
    const float* adj     = (const float*)d_in[1];
    const float* w0      = (const float*)d_in[2];
    const float* b0      = (const float*)d_in[3];
    const float* w1      = (const float*)d_in[4];
    const float* b1      = (const float*)d_in[5];
    const float* a1w     = (const float*)d_in[6];   // (600, 64) row-major
    const float* a1b     = (const float*)d_in[7];
    const float* a2w     = (const float*)d_in[8];
    const float* a2b     = (const float*)d_in[9];
    float* out = (float*)d_out;
    float* ws  = (float*)d_ws;

    float* cW0Ai = ws + OFF_W0AI;
    float* cW0Aj = ws + OFF_W0AJ;
    float* cW1Ai = ws + OFF_W1AI;
    float* cW1Aj = ws + OFF_W1AJ;
    float* bsi0  = ws + OFF_BSI0;
    float* bsj0  = ws + OFF_BSJ0;
    float* bsi1  = ws + OFF_BSI1;
    float* bsj1  = ws + OFF_BSJ1;
    float* h0    = ws + OFF_H0;
    float* si0   = ws + OFF_SI0;
    float* sj0   = ws + OFF_SJ0;
    float* f1    = ws + OFF_F1;
    float* h1    = ws + OFF_H1;
    float* si1   = ws + OFF_SI1;
    float* sj1   = ws + OFF_SJ1;
    float* Zp0   = ws + OFF_ZP0;
    float* Zp1   = ws + OFF_ZP1;
    float* p0    = ws + OFF_P0;
    float* p1    = ws + OFF_P1;

    const float* Ai = a1w;                    // top half (300 x 64)
    const float* Aj = a1w + (long)M_ * H_;    // bottom half

    auto set_job = [](Jobs& jb, int j, const float* A, const float* W,
                      const float* bias, const float* Zp, float* C,
                      int K, int lda, int Cc, int R, int& tiles) {
        jb.A[j] = A; jb.W[j] = W; jb.bias[j] = bias; jb.Zp[j] = Zp; jb.C[j] = C;
        jb.K[j] = K; jb.lda[j] = lda; jb.Cc[j] = Cc; jb.R[j] = R;
        jb.off[j] = tiles;
        tiles += ((R + 31) / 32) * ((Cc + 63) / 64);
    };

    // ---- D1: fused attention-projection weights + bias combos ----
    // si = h@Ai = x@(w@Ai) + (b@Ai);  sj = x@(w@Aj) + (b@Aj + a1b)
    {
        Jobs jb; int tiles = 0;
        set_job(jb, 0, w0, Ai, nullptr, nullptr, cW0Ai, M_, M_, H_, IN_, tiles);
        set_job(jb, 1, w0, Aj, nullptr, nullptr, cW0Aj, M_, M_, H_, IN_, tiles);
        set_job(jb, 2, w1, Ai, nullptr, nullptr, cW1Ai, M_, M_, H_, M_,  tiles);
        set_job(jb, 3, w1, Aj, nullptr, nullptr, cW1Aj, M_, M_, H_, M_,  tiles);
        set_job(jb, 4, b0, Ai, nullptr, nullptr, bsi0,  M_, M_, H_, 1,   tiles);
        set_job(jb, 5, b0, Aj, a1b,     nullptr, bsj0,  M_, M_, H_, 1,   tiles);
        set_job(jb, 6, b1, Ai, nullptr, nullptr, bsi1,  M_, M_, H_, 1,   tiles);
        set_job(jb, 7, b1, Aj, a1b,     nullptr, bsj1,  M_, M_, H_, 1,   tiles);
        jb.njobs = 8;
        gemm_multi<<<dim3(tiles), dim3(128), 0, stream>>>(jb);  // 56 blocks
    }

    // ---- D2: layer-0 node projection + attention features (independent) ----
    {
        Jobs jb; int tiles = 0;
        set_job(jb, 0, feature, w0,    b0,   nullptr, h0,  IN_, IN_, M_, 1024, tiles);
        set_job(jb, 1, feature, cW0Ai, bsi0, nullptr, si0, IN_, IN_, H_, 1024, tiles);
        set_job(jb, 2, feature, cW0Aj, bsj0, nullptr, sj0, IN_, IN_, H_, 1024, tiles);
        jb.njobs = 3;
        gemm_multi<<<dim3(tiles), dim3(128), 0, stream>>>(jb);  // 224 blocks
    }

    // ---- D3: p0 + Zpart0 ----
    attn_p_kernel<<<dim3(16, 16, B_), dim3(256), 0, stream>>>(
        si0, sj0, adj, a2w, a2b, p0, Zp0);

    // ---- D4: f1 = (1/Z0[b]) * p0 @ h0 ----
    {
        Jobs jb; int tiles = 0;
        set_job(jb, 0, p0,               h0,              nullptr, Zp0,       f1,
                N_, N_, M_, N_, tiles);
        set_job(jb, 1, p0 + (long)N_*N_, h0 + (long)N_*M_, nullptr, Zp0 + 256,
                f1 + (long)N_*M_, N_, N_, M_, N_, tiles);
        jb.njobs = 2;
        gemm_multi<<<dim3(tiles), dim3(128), 0, stream>>>(jb);  // 160 blocks
    }

    // ---- D5: layer-1 projections (independent given f1) ----
    {
        Jobs jb; int tiles = 0;
        set_job(jb, 0, f1, w1,    b1,   nullptr, h1,  M_, M_, M_, 1024, tiles);
        set_job(jb, 1, f1, cW1Ai, bsi1, nullptr, si1, M_, M_, H_, 1024, tiles);
        set_job(jb, 2, f1, cW1Aj, bsj1, nullptr, sj1, M_, M_, H_, 1024, tiles);
        jb.njobs = 3;
        gemm_multi<<<dim3(tiles), dim3(128), 0, stream>>>(jb);  // 224 blocks
    }

    // ---- D6: p1 + Zpart1 ----
    attn_p_kernel<<<dim3(16, 16, B_), dim3(256), 0, stream>>>(
        si1, sj1, adj, a2w, a2b, p1, Zp1);

    // ---- D7: out = (1/Z1[b]) * p1 @ h1 ----
    {
        Jobs jb; int tiles = 0;
        set_job(jb, 0, p1,               h1,              nullptr, Zp1,       out,
                N_, N_, M_, N_, tiles);
        set_job(jb, 1, p1 + (long)N_*N_, h1 + (long)N_*M_, nullptr, Zp1 + 256,
                out + (long)N_*M_, N_, N_, M_, N_, tiles);
        jb.njobs = 2;
        gemm_multi<<<dim3(tiles), dim3(128), 0, stream>>>(jb);  // 160 blocks
    }
}

// Round 11
// 212.201 us; speedup vs baseline: 1.1108x; 1.1108x over previous
//
#include <hip/hip_runtime.h>

namespace {

constexpr int N_ = 512;
constexpr int M_ = 300;   // MEM
constexpr int H_ = 64;    // HID
constexpr float SLOPE_ = 0.01f;
constexpr long NN = 262144;   // N*N
constexpr long NM = 153600;   // N*M   (batch stride of h/f planes)
constexpr long NH = 32768;    // N*H   (batch stride of si/g planes)

// ---- workspace plane offsets (floats). K-split GEMMs write two partial
// planes (_A: k<split incl. bias, _B: k>=split); consumers sum the planes
// during their own staging loads (free) — split-K with NO atomics/combine.
// Split points multiple of 4 to keep float4 16B alignment (152 for K=300).
constexpr long O_CW0AI_A = 0;
constexpr long O_CW0AI_B = O_CW0AI_A + 512L*64;
constexpr long O_CW0AJ_A = O_CW0AI_B + 512L*64;
constexpr long O_CW0AJ_B = O_CW0AJ_A + 512L*64;
constexpr long O_CW1AI_A = O_CW0AJ_B + 512L*64;
constexpr long O_CW1AI_B = O_CW1AI_A + 300L*64;
constexpr long O_CW1AJ_A = O_CW1AI_B + 300L*64;
constexpr long O_CW1AJ_B = O_CW1AJ_A + 300L*64;
constexpr long O_BS      = O_CW1AJ_B + 300L*64;   // 8 x 64 bias rows:
// [0]=bsi0_a [1]=bsi0_b [2]=bsj0_a [3]=bsj0_b [4]=bsi1_a [5]=bsi1_b [6]=bsj1_a [7]=bsj1_b
constexpr long O_H0_A  = O_BS + 8*64;
constexpr long O_H0_B  = O_H0_A + 1024L*300;
constexpr long O_SI0_A = O_H0_B + 1024L*300;
constexpr long O_SI0_B = O_SI0_A + 1024L*64;
constexpr long O_SJ0_A = O_SI0_B + 1024L*64;
constexpr long O_SJ0_B = O_SJ0_A + 1024L*64;
constexpr long O_GI_A  = O_SJ0_B + 1024L*64;      // g_i = h0 @ (w1@Ai)
constexpr long O_GI_B  = O_GI_A + 1024L*64;
constexpr long O_GJ_A  = O_GI_B + 1024L*64;
constexpr long O_GJ_B  = O_GJ_A + 1024L*64;
constexpr long O_F1_A  = O_GJ_B + 1024L*64;
constexpr long O_F1_B  = O_F1_A + 1024L*300;
constexpr long O_H1_A  = O_F1_B + 1024L*300;
constexpr long O_H1_B  = O_H1_A + 1024L*300;
constexpr long O_SI1_A = O_H1_B + 1024L*300;
constexpr long O_SI1_B = O_SI1_A + 1024L*64;
constexpr long O_SJ1_A = O_SI1_B + 1024L*64;
constexpr long O_SJ1_B = O_SJ1_A + 1024L*64;
constexpr long O_ZP0   = O_SJ1_B + 1024L*64;      // 512 tile partials / layer
constexpr long O_ZP1   = O_ZP0 + 512;
constexpr long O_P0    = O_ZP1 + 512;
constexpr long O_P1    = O_P0 + 2L*NN;            // end ~13.5 MB

constexpr int MAXJ = 12;
struct Jobs {
    const float* A[MAXJ]; const float* A2[MAXJ];    // A operand (+plane 2)
    const float* W[MAXJ]; const float* W2[MAXJ];    // W operand (+plane 2)
    const float* bias[MAXJ]; const float* bias2[MAXJ];
    const float* Zp[MAXJ];                          // softmax partials (scale)
    float* C[MAXJ]; float* Zout[MAXJ];              // Zout: attn partial sums
    int ks[MAXJ], ke[MAXJ], lda[MAXJ], Cc[MAXJ], R[MAXJ], off[MAXJ], type[MAXJ];
    int njobs;
};

__device__ __forceinline__ float job_scale(const float* Zp)
{
    if (Zp == nullptr) return 1.0f;
    float s0 = 0.f, s1 = 0.f, s2 = 0.f, s3 = 0.f;
    for (int u = 0; u < 256; u += 4) {
        s0 += Zp[u]; s1 += Zp[u + 1]; s2 += Zp[u + 2]; s3 += Zp[u + 3];
    }
    return 1.0f / ((s0 + s1) + (s2 + s3));
}

// ---------------------------------------------------------------------------
// Mixed-job kernel: type 0 = 64x64 GEMM tile (256 thr, 4 waves, 4x4 micro,
// TK=16 — R8's proven geometry: best LDS economy AND enough waves/block;
// grids here keep >=224 blocks so CUs stay filled, fixing R8's idle-CU loss).
// type 1 = attention tile (R6's proven body + two-plane input sum).
//   gemm: C = scale*(sum_k in [ks,ke) (A+A2)[r,k]*(W+W2)[k,c]) (+bias on ks==0)
//   attn: e=leaky_relu(sum_h relu(si+sj)*a2w + a2b); p=adj*exp(e);
//         Zout[b*256+tile]=sum(p). (max-sub skipped: |e|=O(10), fp32-exact;
//         softmax over flat N*N per batch)
// ---------------------------------------------------------------------------
__global__ __launch_bounds__(256)
void mega(Jobs jb, const float* __restrict__ a2w, const float* __restrict__ a2b)
{
    __shared__ __align__(16) char sm[17424];

    const int bid = blockIdx.x;
    int j = jb.njobs - 1;
    while (j > 0 && bid < jb.off[j]) --j;
    const int local = bid - jb.off[j];
    const int t = threadIdx.x;

    if (jb.type[j] == 0) {
        // ---------------- 64x64 GEMM tile ----------------
        float (*As)[68] = reinterpret_cast<float(*)[68]>(sm);            // [k][m]
        float (*Ws)[64] = reinterpret_cast<float(*)[64]>(sm + 16*68*4);  // [k][n]

        const float* __restrict__ A  = jb.A[j];
        const float* __restrict__ A2 = jb.A2[j];
        const float* __restrict__ W  = jb.W[j];
        const float* __restrict__ W2 = jb.W2[j];
        float* __restrict__ C = jb.C[j];
        const int ks = jb.ks[j], ke = jb.ke[j];
        const int lda = jb.lda[j], Cc = jb.Cc[j], R = jb.R[j];

        const int tx   = (Cc + 63) >> 6;
        const int row0 = (local / tx) * 64;
        const int col0 = (local % tx) * 64;

        const int arow = min(row0 + (t >> 2), R - 1);
        const int akg  = (t & 3) * 4;
        const int wk   = t >> 4;
        const int wc   = (t & 15) * 4;
        const int tm0  = (t >> 4) * 4;
        const int tn0  = (t & 15) * 4;

        auto loadA1 = [&](const float* P, int k0) -> float4 {
            const int k = k0 + akg;
            if (k + 3 < ke) return *(const float4*)(P + (long)arow * lda + k);
            float tv[4];
            #pragma unroll
            for (int v = 0; v < 4; ++v)
                tv[v] = (k + v < ke) ? P[(long)arow * lda + k + v] : 0.0f;
            return make_float4(tv[0], tv[1], tv[2], tv[3]);
        };
        auto loadW1 = [&](const float* P, int k0) -> float4 {
            const int gk = k0 + wk;
            const int c  = col0 + wc;
            if (gk < ke && c + 3 < Cc) return *(const float4*)(P + (long)gk * Cc + c);
            float tv[4];
            #pragma unroll
            for (int v = 0; v < 4; ++v)
                tv[v] = (gk < ke && c + v < Cc) ? P[(long)gk * Cc + c + v] : 0.0f;
            return make_float4(tv[0], tv[1], tv[2], tv[3]);
        };
        auto loadA = [&](int k0) -> float4 {
            float4 r = loadA1(A, k0);
            if (A2) {
                const float4 r2 = loadA1(A2, k0);
                r.x += r2.x; r.y += r2.y; r.z += r2.z; r.w += r2.w;
            }
            return r;
        };
        auto loadW = [&](int k0) -> float4 {
            float4 r = loadW1(W, k0);
            if (W2) {
                const float4 r2 = loadW1(W2, k0);
                r.x += r2.x; r.y += r2.y; r.z += r2.z; r.w += r2.w;
            }
            return r;
        };

        float acc[4][4] = {};
        float4 av = loadA(ks);
        float4 wv = loadW(ks);

        for (int k0 = ks; k0 < ke; k0 += 16) {
            As[akg + 0][t >> 2] = av.x;
            As[akg + 1][t >> 2] = av.y;
            As[akg + 2][t >> 2] = av.z;
            As[akg + 3][t >> 2] = av.w;
            *(float4*)&Ws[wk][wc] = wv;
            __syncthreads();

            if (k0 + 16 < ke) {
                av = loadA(k0 + 16);
                wv = loadW(k0 + 16);
            }

            #pragma unroll
            for (int k = 0; k < 16; ++k) {
                const float4 a4 = *(const float4*)&As[k][tm0];
                const float4 w4 = *(const float4*)&Ws[k][tn0];
                const float aa[4] = {a4.x, a4.y, a4.z, a4.w};
                const float ww[4] = {w4.x, w4.y, w4.z, w4.w};
                #pragma unroll
                for (int i = 0; i < 4; ++i)
                    #pragma unroll
                    for (int q = 0; q < 4; ++q)
                        acc[i][q] = fmaf(aa[i], ww[q], acc[i][q]);
            }
            __syncthreads();
        }

        const float scale = job_scale(jb.Zp[j]);
        const int cbase = col0 + tn0;
        float bv[4] = {0.f, 0.f, 0.f, 0.f};
        if (jb.bias[j] != nullptr && ks == 0) {
            const float* b1p = jb.bias[j];
            const float* b2p = jb.bias2[j];
            #pragma unroll
            for (int u = 0; u < 4; ++u)
                if (cbase + u < Cc)
                    bv[u] = b1p[cbase + u] + (b2p ? b2p[cbase + u] : 0.0f);
        }
        #pragma unroll
        for (int i = 0; i < 4; ++i) {
            const int r = row0 + tm0 + i;
            if (r < R) {
                if (cbase + 3 < Cc) {
                    float4 o;
                    o.x = fmaf(acc[i][0], scale, bv[0]);
                    o.y = fmaf(acc[i][1], scale, bv[1]);
                    o.z = fmaf(acc[i][2], scale, bv[2]);
                    o.w = fmaf(acc[i][3], scale, bv[3]);
                    *(float4*)(C + (long)r * Cc + cbase) = o;
                } else {
                    #pragma unroll
                    for (int u = 0; u < 4; ++u)
                        if (cbase + u < Cc)
                            C[(long)r * Cc + cbase + u] = fmaf(acc[i][u], scale, bv[u]);
                }
            }
        }
    } else {
        // ---------------- attention tile ----------------
        float (*Si)[68] = reinterpret_cast<float(*)[68]>(sm);
        float (*Sj)[68] = reinterpret_cast<float(*)[68]>(sm + 32*68*4);
        float* red = reinterpret_cast<float*>(sm + 2*32*68*4);

        const int b  = local >> 8;
        const int r8 = local & 255;
        const int i0 = (r8 >> 4) * 32;
        const int j0 = (r8 & 15) * 32;

        const float* siA = jb.A[j]  + (long)b * NH;
        const float* siB = jb.A2[j] + (long)b * NH;
        const float* sjA = jb.W[j]  + (long)b * NH;
        const float* sjB = jb.W2[j] + (long)b * NH;
        const float* adjb = jb.bias[j] + (long)b * NN;
        float* pb = jb.C[j] + (long)b * NN;

        {   // stage 32x64 tiles, summing the two K-split planes
            const int r  = t >> 3;
            const int hc = (t & 7) * 8;
            const long oi = (long)(i0 + r) * H_ + hc;
            const long oj = (long)(j0 + r) * H_ + hc;
            #pragma unroll
            for (int h = 0; h < 2; ++h) {
                float4 v1 = *(const float4*)(siA + oi + 4*h);
                const float4 v2 = *(const float4*)(siB + oi + 4*h);
                v1.x += v2.x; v1.y += v2.y; v1.z += v2.z; v1.w += v2.w;
                *(float4*)&Si[r][hc + 4*h] = v1;
                float4 u1 = *(const float4*)(sjA + oj + 4*h);
                const float4 u2 = *(const float4*)(sjB + oj + 4*h);
                u1.x += u2.x; u1.y += u2.y; u1.z += u2.z; u1.w += u2.w;
                *(float4*)&Sj[r][hc + 4*h] = u1;
            }
        }
        __syncthreads();

        const int i  = t >> 3;
        const int jl = t & 7;

        float e[4] = {0.f, 0.f, 0.f, 0.f};
        #pragma unroll
        for (int h0 = 0; h0 < H_; h0 += 4) {
            const float4 a4 = *(const float4*)&Si[i][h0];
            const float w0v = a2w[h0 + 0];
            const float w1v = a2w[h0 + 1];
            const float w2v = a2w[h0 + 2];
            const float w3v = a2w[h0 + 3];
            #pragma unroll
            for (int u = 0; u < 4; ++u) {
                const float4 b4 = *(const float4*)&Sj[jl + 8 * u][h0];
                e[u] = fmaf(fmaxf(a4.x + b4.x, 0.f), w0v, e[u]);
                e[u] = fmaf(fmaxf(a4.y + b4.y, 0.f), w1v, e[u]);
                e[u] = fmaf(fmaxf(a4.z + b4.z, 0.f), w2v, e[u]);
                e[u] = fmaf(fmaxf(a4.w + b4.w, 0.f), w3v, e[u]);
            }
        }

        const float a2bv = a2b[0];
        const long rowbase = (long)(i0 + i) * N_ + j0 + jl;
        float lsum = 0.f;
        #pragma unroll
        for (int u = 0; u < 4; ++u) {
            float ev = e[u] + a2bv;
            ev = (ev >= 0.f) ? ev : SLOPE_ * ev;
            const float m  = adjb[rowbase + 8 * u];
            const float pv = m * __expf(ev);
            pb[rowbase + 8 * u] = pv;
            lsum += pv;
        }

        #pragma unroll
        for (int off = 32; off > 0; off >>= 1)
            lsum += __shfl_down(lsum, off, 64);
        if ((t & 63) == 0) red[t >> 6] = lsum;
        __syncthreads();
        if (t == 0)
            jb.Zout[j][b * 256 + r8] = red[0] + red[1] + red[2] + red[3];
    }
}

// ---------------------------------------------------------------------------
// Final GEMM (D6): R6's champion 32x64 / 256-thr / 2x4 geometry (best wall for
// an unsplittable K=512 dispatch of 160 tiles) + W two-plane sum + Zp scale.
// ---------------------------------------------------------------------------
__global__ __launch_bounds__(256)
void gemm32(Jobs jb)
{
    __shared__ __align__(16) float As[32][38];
    __shared__ __align__(16) float Ws[32][64];

    const int bid = blockIdx.x;
    int j = jb.njobs - 1;
    while (j > 0 && bid < jb.off[j]) --j;
    const int local = bid - jb.off[j];

    const float* __restrict__ A  = jb.A[j];
    const float* __restrict__ W  = jb.W[j];
    const float* __restrict__ W2 = jb.W2[j];
    float* __restrict__ C = jb.C[j];
    const int ke = jb.ke[j], lda = jb.lda[j], Cc = jb.Cc[j], R = jb.R[j];

    const int tx   = (Cc + 63) >> 6;
    const int row0 = (local / tx) * 32;
    const int col0 = (local % tx) * 64;

    const int t    = threadIdx.x;
    const int sr   = t >> 3;
    const int sk   = (t & 7) * 4;
    const int arow = min(row0 + sr, R - 1);
    const int wk   = t >> 4;
    const int wc   = (t & 15) * 4;
    const int tm0  = (t >> 4) * 2;
    const int tn0  = (t & 15) * 4;

    auto loadA = [&](int k0) -> float4 {
        const int k = k0 + sk;
        if (k + 3 < ke) return *(const float4*)(A + (long)arow * lda + k);
        float tv[4];
        #pragma unroll
        for (int v = 0; v < 4; ++v)
            tv[v] = (k + v < ke) ? A[(long)arow * lda + k + v] : 0.0f;
        return make_float4(tv[0], tv[1], tv[2], tv[3]);
    };
    auto loadW = [&](int k0, int s) -> float4 {
        const int gk = k0 + wk + 16 * s;
        const int c  = col0 + wc;
        float4 r = make_float4(0.f, 0.f, 0.f, 0.f);
        if (gk < ke) {
            if (c + 3 < Cc) {
                r = *(const float4*)(W + (long)gk * Cc + c);
                if (W2) {
                    const float4 r2 = *(const float4*)(W2 + (long)gk * Cc + c);
                    r.x += r2.x; r.y += r2.y; r.z += r2.z; r.w += r2.w;
                }
            } else {
                float tv[4];
                #pragma unroll
                for (int v = 0; v < 4; ++v) {
                    tv[v] = (c + v < Cc) ? W[(long)gk * Cc + c + v] : 0.0f;
                    if (W2 && c + v < Cc) tv[v] += W2[(long)gk * Cc + c + v];
                }
                r = make_float4(tv[0], tv[1], tv[2], tv[3]);
            }
        }
        return r;
    };

    float acc[2][4] = {};
    float4 av  = loadA(0);
    float4 wv0 = loadW(0, 0);
    float4 wv1 = loadW(0, 1);

    for (int k0 = 0; k0 < ke; k0 += 32) {
        As[sk + 0][sr] = av.x;
        As[sk + 1][sr] = av.y;
        As[sk + 2][sr] = av.z;
        As[sk + 3][sr] = av.w;
        *(float4*)&Ws[wk][wc]      = wv0;
        *(float4*)&Ws[wk + 16][wc] = wv1;
        __syncthreads();

        if (k0 + 32 < ke) {
            av  = loadA(k0 + 32);
            wv0 = loadW(k0 + 32, 0);
            wv1 = loadW(k0 + 32, 1);
        }

        #pragma unroll
        for (int k = 0; k < 32; ++k) {
            const float a0 = As[k][tm0];
            const float a1 = As[k][tm0 + 1];
            const float4 w4 = *(const float4*)&Ws[k][tn0];
            acc[0][0] = fmaf(a0, w4.x, acc[0][0]);
            acc[0][1] = fmaf(a0, w4.y, acc[0][1]);
            acc[0][2] = fmaf(a0, w4.z, acc[0][2]);
            acc[0][3] = fmaf(a0, w4.w, acc[0][3]);
            acc[1][0] = fmaf(a1, w4.x, acc[1][0]);
            acc[1][1] = fmaf(a1, w4.y, acc[1][1]);
            acc[1][2] = fmaf(a1, w4.z, acc[1][2]);
            acc[1][3] = fmaf(a1, w4.w, acc[1][3]);
        }
        __syncthreads();
    }

    const float scale = job_scale(jb.Zp[j]);
    const int cbase = col0 + tn0;
    #pragma unroll
    for (int i = 0; i < 2; ++i) {
        const int r = row0 + tm0 + i;
        if (r < R) {
            if (cbase + 3 < Cc) {
                float4 o;
                o.x = acc[i][0] * scale;
                o.y = acc[i][1] * scale;
                o.z = acc[i][2] * scale;
                o.w = acc[i][3] * scale;
                *(float4*)(C + (long)r * Cc + cbase) = o;
            } else {
                #pragma unroll
                for (int u = 0; u < 4; ++u)
                    if (cbase + u < Cc)
                        C[(long)r * Cc + cbase + u] = acc[i][u] * scale;
            }
        }
    }
}

} // namespace

extern "C" void kernel_launch(void* const* d_in, const int* in_sizes, int n_in,
                              void* d_out, int out_size, void* d_ws, size_t ws_size,
                              hipStream_t stream)
{
    const float* feature = (const float*)d_in[0];
    const float* adj     = (const float*)d_in[1];
    const float* w0      = (const float*)d_in[2];
    const float* b0      = (const float*)d_in[3];
    const float* w1      = (const float*)d_in[4];
    const float* b1      = (const float*)d_in[5];
    const float* a1w     = (const float*)d_in[6];   // (600,64): Ai | Aj
    const float* a1b     = (const float*)d_in[7];
    const float* a2w     = (const float*)d_in[8];
    const float* a2b     = (const float*)d_in[9];
    float* out = (float*)d_out;
    float* ws  = (float*)d_ws;

    const float* Ai = a1w;
    const float* Aj = a1w + (long)M_ * H_;

    float* cW0AiA = ws + O_CW0AI_A; float* cW0AiB = ws + O_CW0AI_B;
    float* cW0AjA = ws + O_CW0AJ_A; float* cW0AjB = ws + O_CW0AJ_B;
    float* cW1AiA = ws + O_CW1AI_A; float* cW1AiB = ws + O_CW1AI_B;
    float* cW1AjA = ws + O_CW1AJ_A; float* cW1AjB = ws + O_CW1AJ_B;
    float* bs     = ws + O_BS;   // 8 rows of 64
    float* h0A = ws + O_H0_A;  float* h0B = ws + O_H0_B;
    float* si0A = ws + O_SI0_A; float* si0B = ws + O_SI0_B;
    float* sj0A = ws + O_SJ0_A; float* sj0B = ws + O_SJ0_B;
    float* giA = ws + O_GI_A;  float* giB = ws + O_GI_B;
    float* gjA = ws + O_GJ_A;  float* gjB = ws + O_GJ_B;
    float* f1A = ws + O_F1_A;  float* f1B = ws + O_F1_B;
    float* h1A = ws + O_H1_A;  float* h1B = ws + O_H1_B;
    float* si1A = ws + O_SI1_A; float* si1B = ws + O_SI1_B;
    float* sj1A = ws + O_SJ1_A; float* sj1B = ws + O_SJ1_B;
    float* Zp0 = ws + O_ZP0;   float* Zp1 = ws + O_ZP1;
    float* p0  = ws + O_P0;    float* p1  = ws + O_P1;

    struct Builder {
        Jobs jb{}; int tiles = 0; int n = 0;
        void gem(const float* A, const float* A2, const float* W, const float* W2,
                 const float* bias, const float* bias2, const float* Zp, float* C,
                 int ks, int ke, int lda, int Cc, int R) {
            jb.A[n]=A; jb.A2[n]=A2; jb.W[n]=W; jb.W2[n]=W2;
            jb.bias[n]=bias; jb.bias2[n]=bias2; jb.Zp[n]=Zp; jb.C[n]=C; jb.Zout[n]=nullptr;
            jb.ks[n]=ks; jb.ke[n]=ke; jb.lda[n]=lda; jb.Cc[n]=Cc; jb.R[n]=R;
            jb.off[n]=tiles; jb.type[n]=0;
            tiles += ((R + 63)/64) * ((Cc + 63)/64);
            jb.njobs = ++n;
        }
        void att(const float* siA_, const float* siB_, const float* sjA_,
                 const float* sjB_, const float* adj_, float* p_, float* Z_) {
            jb.A[n]=siA_; jb.A2[n]=siB_; jb.W[n]=sjA_; jb.W2[n]=sjB_;
            jb.bias[n]=adj_; jb.bias2[n]=nullptr; jb.Zp[n]=nullptr; jb.C[n]=p_; jb.Zout[n]=Z_;
            jb.ks[n]=0; jb.ke[n]=0; jb.lda[n]=0; jb.Cc[n]=0; jb.R[n]=0;
            jb.off[n]=tiles; jb.type[n]=1;
            tiles += 512;
            jb.njobs = ++n;
        }
    };
    constexpr int KS = 152;   // K=300 split point (multiple of 4: alignment)

    // D1: fused attention-projection weights + bias rows (input-only), K-split
    {
        Builder b;
        b.gem(w0, nullptr, Ai, nullptr, nullptr, nullptr, nullptr, cW0AiA, 0, KS, M_, H_, 512);
        b.gem(w0, nullptr, Ai, nullptr, nullptr, nullptr, nullptr, cW0AiB, KS, M_, M_, H_, 512);
        b.gem(w0, nullptr, Aj, nullptr, nullptr, nullptr, nullptr, cW0AjA, 0, KS, M_, H_, 512);
        b.gem(w0, nullptr, Aj, nullptr, nullptr, nullptr, nullptr, cW0AjB, KS, M_, M_, H_, 512);
        b.gem(b0, nullptr, Ai, nullptr, nullptr, nullptr, nullptr, bs + 0*64, 0, KS, M_, H_, 1);
        b.gem(b0, nullptr, Ai, nullptr, nullptr, nullptr, nullptr, bs + 1*64, KS, M_, M_, H_, 1);
        b.gem(b0, nullptr, Aj, nullptr, a1b,     nullptr, nullptr, bs + 2*64, 0, KS, M_, H_, 1);
        b.gem(b0, nullptr, Aj, nullptr, nullptr, nullptr, nullptr, bs + 3*64, KS, M_, M_, H_, 1);
        b.gem(b1, nullptr, Ai, nullptr, nullptr, nullptr, nullptr, bs + 4*64, 0, KS, M_, H_, 1);
        b.gem(b1, nullptr, Ai, nullptr, nullptr, nullptr, nullptr, bs + 5*64, KS, M_, M_, H_, 1);
        b.gem(b1, nullptr, Aj, nullptr, a1b,     nullptr, nullptr, bs + 6*64, 0, KS, M_, H_, 1);
        b.gem(b1, nullptr, Aj, nullptr, nullptr, nullptr, nullptr, bs + 7*64, KS, M_, M_, H_, 1);
        mega<<<dim3(b.tiles), dim3(256), 0, stream>>>(b.jb, a2w, a2b);  // 40
    }
    // D2: h0 | si0 | sj0 | cW1Ai | cW1Aj  (all K-split)
    {
        Builder b;
        b.gem(feature, nullptr, w0, nullptr, b0, nullptr, nullptr, h0A, 0, 256, 512, M_, 1024);
        b.gem(feature, nullptr, w0, nullptr, nullptr, nullptr, nullptr, h0B, 256, 512, 512, M_, 1024);
        b.gem(feature, nullptr, cW0AiA, cW0AiB, bs+0*64, bs+1*64, nullptr, si0A, 0, 256, 512, H_, 1024);
        b.gem(feature, nullptr, cW0AiA, cW0AiB, nullptr, nullptr, nullptr, si0B, 256, 512, 512, H_, 1024);
        b.gem(feature, nullptr, cW0AjA, cW0AjB, bs+2*64, bs+3*64, nullptr, sj0A, 0, 256, 512, H_, 1024);
        b.gem(feature, nullptr, cW0AjA, cW0AjB, nullptr, nullptr, nullptr, sj0B, 256, 512, 512, H_, 1024);
        b.gem(w1, nullptr, Ai, nullptr, nullptr, nullptr, nullptr, cW1AiA, 0, KS, M_, H_, 300);
        b.gem(w1, nullptr, Ai, nullptr, nullptr, nullptr, nullptr, cW1AiB, KS, M_, M_, H_, 300);
        b.gem(w1, nullptr, Aj, nullptr, nullptr, nullptr, nullptr, cW1AjA, 0, KS, M_, H_, 300);
        b.gem(w1, nullptr, Aj, nullptr, nullptr, nullptr, nullptr, cW1AjB, KS, M_, M_, H_, 300);
        mega<<<dim3(b.tiles), dim3(256), 0, stream>>>(b.jb, a2w, a2b);  // 244
    }
    // D3: g_i/g_j = h0 @ cW1Ai/Aj  (for si1 = (1/Z0)p0@g + bias) | attn0
    {
        Builder b;
        b.gem(h0A, h0B, cW1AiA, cW1AiB, nullptr, nullptr, nullptr, giA, 0, KS, M_, H_, 1024);
        b.gem(h0A, h0B, cW1AiA, cW1AiB, nullptr, nullptr, nullptr, giB, KS, M_, M_, H_, 1024);
        b.gem(h0A, h0B, cW1AjA, cW1AjB, nullptr, nullptr, nullptr, gjA, 0, KS, M_, H_, 1024);
        b.gem(h0A, h0B, cW1AjA, cW1AjB, nullptr, nullptr, nullptr, gjB, KS, M_, M_, H_, 1024);
        b.att(si0A, si0B, sj0A, sj0B, adj, p0, Zp0);
        mega<<<dim3(b.tiles), dim3(256), 0, stream>>>(b.jb, a2w, a2b);  // 576
    }
    // D4: f1 = (1/Z0)p0@h0 | si1/sj1 = (1/Z0)p0@g + bias   (all K-split)
    {
        Builder b;
        for (int bt = 0; bt < 2; ++bt) {
            const float* pA = p0 + (long)bt * NN;
            const float* Zq = Zp0 + bt * 256;
            b.gem(pA, nullptr, h0A + bt*NM, h0B + bt*NM, nullptr, nullptr, Zq, f1A + bt*NM, 0, 256, 512, M_, 512);
            b.gem(pA, nullptr, h0A + bt*NM, h0B + bt*NM, nullptr, nullptr, Zq, f1B + bt*NM, 256, 512, 512, M_, 512);
            b.gem(pA, nullptr, giA + bt*NH, giB + bt*NH, bs+4*64, bs+5*64, Zq, si1A + bt*NH, 0, 256, 512, H_, 512);
            b.gem(pA, nullptr, giA + bt*NH, giB + bt*NH, nullptr, nullptr, Zq, si1B + bt*NH, 256, 512, 512, H_, 512);
            b.gem(pA, nullptr, gjA + bt*NH, gjB + bt*NH, bs+6*64, bs+7*64, Zq, sj1A + bt*NH, 0, 256, 512, H_, 512);
            b.gem(pA, nullptr, gjA + bt*NH, gjB + bt*NH, nullptr, nullptr, Zq, sj1B + bt*NH, 256, 512, 512, H_, 512);
        }
        mega<<<dim3(b.tiles), dim3(256), 0, stream>>>(b.jb, a2w, a2b);  // 224
    }
    // D5: h1 = f1@w1 + b1 (K-split) | attn1
    {
        Builder b;
        b.gem(f1A, f1B, w1, nullptr, b1, nullptr, nullptr, h1A, 0, KS, M_, M_, 1024);
        b.gem(f1A, f1B, w1, nullptr, nullptr, nullptr, nullptr, h1B, KS, M_, M_, M_, 1024);
        b.att(si1A, si1B, sj1A, sj1B, adj, p1, Zp1);
        mega<<<dim3(b.tiles), dim3(256), 0, stream>>>(b.jb, a2w, a2b);  // 672
    }
    // D6: out = (1/Z1) p1 @ (h1A+h1B)   (32x64 kernel, unsplit final K)
    {
        Builder b;
        b.jb.njobs = 0; b.n = 0; b.tiles = 0;
        for (int bt = 0; bt < 2; ++bt) {
            b.jb.A[b.n]=p1 + (long)bt*NN; b.jb.A2[b.n]=nullptr;
            b.jb.W[b.n]=h1A + bt*NM; b.jb.W2[b.n]=h1B + bt*NM;
            b.jb.bias[b.n]=nullptr; b.jb.bias2[b.n]=nullptr;
            b.jb.Zp[b.n]=Zp1 + bt*256; b.jb.C[b.n]=out + (long)bt*NM; b.jb.Zout[b.n]=nullptr;
            b.jb.ks[b.n]=0; b.jb.ke[b.n]=512; b.jb.lda[b.n]=512; b.jb.Cc[b.n]=M_; b.jb.R[b.n]=512;
            b.jb.off[b.n]=b.tiles; b.jb.type[b.n]=0;
            b.tiles += (512/32) * ((M_ + 63)/64);   // 16 x 5 = 80
            b.jb.njobs = ++b.n;
        }
        gemm32<<<dim3(b.tiles), dim3(256), 0, stream>>>(b.jb);  // 160
    }
}